// Round 7
// baseline (161.934 us; speedup 1.0000x reference)
//
#include <hip/hip_runtime.h>
#include <hip/hip_bf16.h>
#include <cstdint>

// MultiHeadAttention: out = ( softmax(causal((X Wq^T)(X Wk^T)^T / 8)) (X Wv^T) ) Wo^T
// B=2, S=2048, D_MODEL=1024, H=16, D_HEAD=64. All MFMA bf16, accum fp32.
//
// Workspace layout (64 MB):
//  [0,8M)    Qp  bf16 [16][4096][64]  per-head packed, pre-scaled by log2e/8
//  [8,16M)   Kp  bf16 [16][4096][64]  per-head packed
//  [16,24M)  Vt  bf16 [1024][4096]    V transposed (row = h*64+d, col = token)
//  [24,32M)  Ctx bf16 [4096][1024]
//  [32,56M)  Xq/Xk/Xv bf16 inputs
//  [56,64M)  Wq/Wk/Wv/Wo bf16 weights

typedef unsigned short u16;
typedef u16 u16x4 __attribute__((ext_vector_type(4)));
typedef u16 u16x8 __attribute__((ext_vector_type(8)));
typedef unsigned u32x4 __attribute__((ext_vector_type(4)));
typedef __bf16 bf16x8 __attribute__((ext_vector_type(8)));
typedef float f32x4 __attribute__((ext_vector_type(4)));
typedef float f32x16 __attribute__((ext_vector_type(16)));

#define S_LEN 2048
#define DM 1024
#define NH 16
#define DH 64
#define BATCH 2
#define MTOT (BATCH*S_LEN)   // 4096

__device__ __forceinline__ u16 f2bf(float f) {
  union { float f; unsigned u; } v; v.f = f;
  unsigned r = v.u + 0x7FFFu + ((v.u >> 16) & 1u);   // RNE
  return (u16)(r >> 16);
}

__device__ __forceinline__ f32x4 mfma16(u16x8 a, u16x8 b, f32x4 c) {
  return __builtin_amdgcn_mfma_f32_16x16x32_bf16(
      __builtin_bit_cast(bf16x8, a), __builtin_bit_cast(bf16x8, b), c, 0, 0, 0);
}
__device__ __forceinline__ f32x16 mfma32(u16x8 a, u16x8 b, f32x16 c) {
  return __builtin_amdgcn_mfma_f32_32x32x16_bf16(
      __builtin_bit_cast(bf16x8, a), __builtin_bit_cast(bf16x8, b), c, 0, 0, 0);
}
__device__ __forceinline__ unsigned cvtpk_bf16(float lo, float hi) {
  unsigned r;
  asm("v_cvt_pk_bf16_f32 %0, %1, %2" : "=v"(r) : "v"(lo), "v"(hi));
  return r;
}
__device__ __forceinline__ void permswap(unsigned &a, unsigned &b) {
  asm volatile("v_permlane32_swap_b32 %0, %1" : "+v"(a), "+v"(b));
}
// async global -> LDS, 16B per lane; LDS dest = wave-uniform base + lane*16
__device__ __forceinline__ void gload16(const u16* g, u16* l) {
  __builtin_amdgcn_global_load_lds(
      (const __attribute__((address_space(1))) unsigned int*)g,
      (__attribute__((address_space(3))) unsigned int*)l, 16, 0, 0);
}

// ---------------------------------------------------------------- fp32->bf16
__global__ __launch_bounds__(256) void cvt_kernel(
    const float* __restrict__ s0, const float* __restrict__ s1,
    const float* __restrict__ s2, const float* __restrict__ s3,
    const float* __restrict__ s4, const float* __restrict__ s5,
    const float* __restrict__ s6,
    u16* __restrict__ d0, u16* __restrict__ d1, u16* __restrict__ d2,
    u16* __restrict__ d3, u16* __restrict__ d4, u16* __restrict__ d5,
    u16* __restrict__ d6) {
  const int y = blockIdx.y;
  const float* s; u16* d; int n;
  switch (y) {
    case 0: s = s0; d = d0; n = MTOT*DM; break;
    case 1: s = s1; d = d1; n = MTOT*DM; break;
    case 2: s = s2; d = d2; n = MTOT*DM; break;
    case 3: s = s3; d = d3; n = DM*DM;   break;
    case 4: s = s4; d = d4; n = DM*DM;   break;
    case 5: s = s5; d = d5; n = DM*DM;   break;
    default: s = s6; d = d6; n = DM*DM;  break;
  }
  int i = (blockIdx.x * 256 + threadIdx.x) * 4;
  if (i >= n) return;
  f32x4 v = *(const f32x4*)&s[i];
  u16x4 o;
  o[0] = f2bf(v[0]); o[1] = f2bf(v[1]); o[2] = f2bf(v[2]); o[3] = f2bf(v[3]);
  *(u16x4*)&d[i] = o;
}

// ---------------------------------------------------------------- GEMM C=A*B^T
// m97 structure: 128x128 tile, BK=32, 4 waves (2x2), global_load_lds width-16
// staging into LINEAR LDS [128][32], 2 barriers per K-step, 4x4 16x16x32 MFMA.
#define BM 128
#define BN 128
#define BKK 32

template<int MODE>
__device__ __forceinline__ void gemm_core(const u16* __restrict__ A,
                                          const u16* __restrict__ Bw,
                                          void* __restrict__ Cv,
                                          int K, float scale) {
  __shared__ u16 As[BM * BKK];
  __shared__ u16 Bs[BN * BKK];
  const int tid  = threadIdx.x;
  const int lane = tid & 63, w = tid >> 6;
  const int g = lane >> 4, r16 = lane & 15;
  const int wm = w >> 1, wn = w & 1;
  const int rowBase = blockIdx.y * BM;
  const int colBase = blockIdx.x * BN;
  f32x4 acc[4][4] = {};
  const int srow = lane >> 2;
  const int skc  = (lane & 3) * 8;
  const u16* gA[2]; const u16* gB[2]; u16* lA[2]; u16* lB[2];
#pragma unroll
  for (int j = 0; j < 2; j++) {
    const int c = w * 2 + j;
    gA[j] = &A [(size_t)(rowBase + c * 16 + srow) * K + skc];
    gB[j] = &Bw[(size_t)(colBase + c * 16 + srow) * K + skc];
    lA[j] = &As[c * 512];
    lB[j] = &Bs[c * 512];
  }
  for (int k0 = 0; k0 < K; k0 += BKK) {
    __syncthreads();
#pragma unroll
    for (int j = 0; j < 2; j++) {
      gload16(gA[j] + k0, lA[j]);
      gload16(gB[j] + k0, lB[j]);
    }
    __syncthreads();
    u16x8 af[4], bfv[4];
#pragma unroll
    for (int i = 0; i < 4; i++) af[i]  = *(const u16x8*)&As[(wm*64 + i*16 + r16) * BKK + g*8];
#pragma unroll
    for (int j = 0; j < 4; j++) bfv[j] = *(const u16x8*)&Bs[(wn*64 + j*16 + r16) * BKK + g*8];
    __builtin_amdgcn_s_setprio(1);
#pragma unroll
    for (int i = 0; i < 4; i++)
#pragma unroll
      for (int j = 0; j < 4; j++) acc[i][j] = mfma16(af[i], bfv[j], acc[i][j]);
    __builtin_amdgcn_s_setprio(0);
  }
  // C/D layout: col = lane&15, row = 4*(lane>>4)+reg
#pragma unroll
  for (int i = 0; i < 4; i++) {
#pragma unroll
    for (int j = 0; j < 4; j++) {
      int row = rowBase + wm*64 + i*16 + 4*g;
      int col = colBase + wn*64 + j*16 + r16;
      if (MODE == 0) {
        u16* O = (u16*)Cv;
        int head = col >> 6, d = col & 63;
#pragma unroll
        for (int r = 0; r < 4; r++)
          O[((size_t)head * MTOT + row + r) * DH + d] = f2bf(acc[i][j][r] * scale);
      } else if (MODE == 1) {
        u16x4 o;
#pragma unroll
        for (int r = 0; r < 4; r++) o[r] = f2bf(acc[i][j][r]);
        *(u16x4*)&((u16*)Cv)[(size_t)col * MTOT + row] = o;
      } else {
#pragma unroll
        for (int r = 0; r < 4; r++)
          ((float*)Cv)[(size_t)(row + r) * DM + col] = acc[i][j][r];
      }
    }
  }
}

__global__ __launch_bounds__(256) void qkv_proj_kernel(
    const u16* __restrict__ Xq, const u16* __restrict__ Xk, const u16* __restrict__ Xv,
    const u16* __restrict__ Wq, const u16* __restrict__ Wk, const u16* __restrict__ Wv,
    u16* __restrict__ Qp, u16* __restrict__ Kp, u16* __restrict__ Vt) {
  const int z = blockIdx.z;
  // Q pre-scaled by (1/sqrt(64)) * log2(e) -> softmax in exp2 domain
  if (z == 0)      gemm_core<0>(Xq, Wq, Qp, DM, 0.125f * 1.44269504f);
  else if (z == 1) gemm_core<0>(Xk, Wk, Kp, DM, 1.0f);
  else             gemm_core<1>(Xv, Wv, Vt, DM, 1.0f);
}

__global__ __launch_bounds__(256) void out_proj_kernel(
    const u16* __restrict__ Ctx, const u16* __restrict__ Wo, float* __restrict__ Out) {
  gemm_core<2>(Ctx, Wo, Out, DM, 1.0f);
}

// ---------------------------------------------------------------- flash attn
// Grid 2048 blocks, 4 waves/block, kv-split x4 merged via LDS.
// Round-7 changes (latency exposure, single-variable on attn):
//  (a) V loads issued BEFORE the K prefetch: vmcnt retires in issue order,
//      so PV's wait on V becomes vmcnt(16) and the K prefetch stays in
//      flight across the tile boundary (was: vmcnt(0) drained it each tile).
//  (b) per-XCD head-sequential block order: 64 consecutive blocks per bh ->
//      1MB K+V working set per XCD L2 (was 4MB = whole L2, thrashing).
//  (c) tree-reduced pmax/psum (dep chain 32 -> ~6).
// Kept: swapped QK^T, exp2 softmax, T12 cvt_pk+permlane, T13 defer-max,
// T5 setprio, launch_bounds(256,2) (no forced spill; round-4 post-mortem).

#define LOADK(KF, T)                                                           \
  {                                                                            \
    const int kv0_ = (T) * 64;                                                 \
    _Pragma("unroll")                                                          \
    for (int ds = 0; ds < 4; ds++) {                                           \
      KF[2*ds]   = *(const u16x8*)&Kbase[(size_t)(kv0_ + q32) * DH + ds*16 + hi*8];      \
      KF[2*ds+1] = *(const u16x8*)&Kbase[(size_t)(kv0_ + 32 + q32) * DH + ds*16 + hi*8]; \
    }                                                                          \
  }

#define TILE_BODY(T, PF)                                                       \
  {                                                                            \
    const int kv0 = (T) * 64;                                                  \
    f32x16 s0 = {}, s1 = {};                                                   \
    __builtin_amdgcn_s_setprio(1);                                             \
    _Pragma("unroll")                                                          \
    for (int ds = 0; ds < 4; ds++) {                                           \
      s0 = mfma32(kA[2*ds],   qf[ds], s0);                                     \
      s1 = mfma32(kA[2*ds+1], qf[ds], s1);                                     \
    }                                                                          \
    __builtin_amdgcn_s_setprio(0);                                             \
    u16x8 vf[8];                       /* V first (older in vmcnt queue) */    \
    _Pragma("unroll")                                                          \
    for (int ks = 0; ks < 4; ks++) {                                           \
      vf[2*ks]   = *(const u16x8*)&Vbase[(size_t)q32 * MTOT        + kv0 + ks*16 + hi*8]; \
      vf[2*ks+1] = *(const u16x8*)&Vbase[(size_t)(32 + q32) * MTOT + kv0 + ks*16 + hi*8]; \
    }                                                                          \
    if (PF) LOADK(kA, (T) + 4);        /* K prefetch after V (newer) */        \
    if ((T) == ntiles - 1) {                                                   \
      const int qg = qbase + q32;                                              \
      _Pragma("unroll")                                                        \
      for (int r = 0; r < 16; r++) {                                           \
        int kvr = kv0 + (r & 3) + 8 * (r >> 2) + 4 * hi;                       \
        if (kvr > qg)      s0[r] = -1e30f;                                     \
        if (kvr + 32 > qg) s1[r] = -1e30f;                                     \
      }                                                                        \
    }                                                                          \
    float mx[8];                        /* tree max, dep depth ~6 */           \
    _Pragma("unroll")                                                          \
    for (int r = 0; r < 8; r++)                                                \
      mx[r] = fmaxf(fmaxf(s0[r], s0[r + 8]), fmaxf(s1[r], s1[r + 8]));         \
    _Pragma("unroll")                                                          \
    for (int r = 0; r < 4; r++) mx[r] = fmaxf(mx[r], mx[r + 4]);               \
    float pmax = fmaxf(fmaxf(mx[0], mx[2]), fmaxf(mx[1], mx[3]));              \
    pmax = fmaxf(pmax, __shfl_xor(pmax, 32, 64));                              \
    if (__ballot(pmax > m + 11.5f)) {   /* defer-max, THR = 8/ln2 */           \
      float mnew = fmaxf(m, pmax);                                             \
      float alpha = exp2f(m - mnew);                                           \
      l *= alpha; m = mnew;                                                    \
      _Pragma("unroll")                                                        \
      for (int r = 0; r < 16; r++) {                                           \
        float fsc = __shfl(alpha, (r & 3) + 8 * (r >> 2) + 4 * hi, 64);        \
        ctx0[r] *= fsc; ctx1[r] *= fsc;                                        \
      }                                                                        \
    }                                                                          \
    _Pragma("unroll")                                                          \
    for (int r = 0; r < 16; r++) s0[r] = exp2f(s0[r] - m);                     \
    _Pragma("unroll")                                                          \
    for (int r = 0; r < 16; r++) s1[r] = exp2f(s1[r] - m);                     \
    f32x16 sv = s0 + s1;                /* tree sum, dep depth ~6 */           \
    float p8[8];                                                               \
    _Pragma("unroll")                                                          \
    for (int r = 0; r < 8; r++) p8[r] = sv[r] + sv[r + 8];                     \
    _Pragma("unroll")                                                          \
    for (int r = 0; r < 4; r++) p8[r] += p8[r + 4];                            \
    float psum = (p8[0] + p8[2]) + (p8[1] + p8[3]);                            \
    psum += __shfl_xor(psum, 32, 64);                                          \
    l += psum;                                                                 \
    u16x8 pa[4];                                                               \
    _Pragma("unroll")                                                          \
    for (int tt = 0; tt < 2; tt++) {                                           \
      unsigned pk[8];                                                          \
      _Pragma("unroll")                                                        \
      for (int i = 0; i < 8; i++)                                              \
        pk[i] = cvtpk_bf16(tt ? s1[2*i] : s0[2*i], tt ? s1[2*i+1] : s0[2*i+1]);\
      permswap(pk[0], pk[2]); permswap(pk[1], pk[3]);                          \
      permswap(pk[4], pk[6]); permswap(pk[5], pk[7]);                          \
      u32x4 w0 = {pk[0], pk[1], pk[2], pk[3]};                                 \
      u32x4 w1 = {pk[4], pk[5], pk[6], pk[7]};                                 \
      pa[2*tt]   = __builtin_bit_cast(u16x8, w0);                              \
      pa[2*tt+1] = __builtin_bit_cast(u16x8, w1);                              \
    }                                                                          \
    __builtin_amdgcn_s_setprio(1);                                             \
    _Pragma("unroll")                                                          \
    for (int ks = 0; ks < 4; ks++) {                                           \
      ctx0 = mfma32(pa[ks], vf[2*ks],   ctx0);                                 \
      ctx1 = mfma32(pa[ks], vf[2*ks+1], ctx1);                                 \
    }                                                                          \
    __builtin_amdgcn_s_setprio(0);                                             \
  }

__global__ __launch_bounds__(256, 2) void attn_kernel(const u16* __restrict__ Qp,
                                                      const u16* __restrict__ Kp,
                                                      const u16* __restrict__ Vt,
                                                      u16* __restrict__ Ctx) {
  __shared__ float mlds[4][64];        // per-wave partial max
  __shared__ float llds[3][64];        // waves 1..3 scaled l
  __shared__ float clds[3][32][64];    // waves 1..3 scaled ctx (r<16: ctx0)
  const int tid = threadIdx.x;
  const int lane = tid & 63, kvh = tid >> 6;
  const int q32 = lane & 31, hi = lane >> 5;
  // XCD-bijective remap (assumes XCD = flat % 8). Head-sequential within
  // each XCD: 64 consecutive blocks share one bh -> 1MB K+V in the 4MB L2.
  // Heavy q-chunks first within each head (tail backfilled by next head).
  const int flat = blockIdx.x;                 // 0..2047
  const int xcd = flat & 7, idx = flat >> 3;   // idx 0..255
  const int bh = xcd * 4 + (idx >> 6);
  const int qc = 63 - (idx & 63);              // 0..63, heavy first
  const int bb = bh >> 4, h = bh & 15;
  const int qbase = qc * 32;

  const u16* Qbase = Qp + (size_t)(h * MTOT + bb * S_LEN) * DH;
  const u16* Kbase = Kp + (size_t)(h * MTOT + bb * S_LEN) * DH;
  const u16* Vbase = Vt + (size_t)(h * DH) * MTOT + bb * S_LEN;

  u16x8 qf[4];
#pragma unroll
  for (int ds = 0; ds < 4; ds++)
    qf[ds] = *(const u16x8*)&Qbase[(size_t)(qbase + q32) * DH + ds * 16 + hi * 8];

  f32x16 ctx0 = {}, ctx1 = {};
  float m = -3.0e38f, l = 0.f;
  const int ntiles = ((qbase + 31) >> 6) + 1;

  // wave kvh processes tiles t = kvh, kvh+4, ...; K prefetched in-body
  u16x8 kA[8];
  if (kvh < ntiles) {
    LOADK(kA, kvh);
    for (int t = kvh; t < ntiles; t += 4) {
      TILE_BODY(t, (t + 4 < ntiles));
    }
  }

  // ---- 4-way merge of kv-split partials via LDS ----
  mlds[kvh][lane] = m;
  __syncthreads();
  const float M = fmaxf(fmaxf(mlds[0][lane], mlds[1][lane]),
                        fmaxf(mlds[2][lane], mlds[3][lane]));
  const float alpha = exp2f(m - M);   // 0 when this wave had no tiles
  l *= alpha;
  if (kvh != 0) {
#pragma unroll
    for (int r = 0; r < 16; r++) {
      float fa = __shfl(alpha, (r & 3) + 8 * (r >> 2) + 4 * hi, 64);
      clds[kvh - 1][r][lane]      = ctx0[r] * fa;
      clds[kvh - 1][16 + r][lane] = ctx1[r] * fa;
    }
    llds[kvh - 1][lane] = l;
  }
  __syncthreads();
  if (kvh == 0) {
    const float L = l + llds[0][lane] + llds[1][lane] + llds[2][lane];
    const float linv = 1.f / L;
#pragma unroll
    for (int r = 0; r < 16; r++) {
      int qr = (r & 3) + 8 * (r >> 2) + 4 * hi;
      float fa = __shfl(alpha, qr, 64);
      float fl = __shfl(linv, qr, 64);
      float o0 = ctx0[r] * fa + clds[0][r][lane] + clds[1][r][lane] + clds[2][r][lane];
      float o1 = ctx1[r] * fa + clds[0][16 + r][lane] + clds[1][16 + r][lane] + clds[2][16 + r][lane];
      size_t grow = (size_t)(bb * S_LEN + qbase + qr) * DM + h * DH;
      Ctx[grow + q32]      = f2bf(o0 * fl);
      Ctx[grow + 32 + q32] = f2bf(o1 * fl);
    }
  }
}

// ---------------------------------------------------------------- launch
extern "C" void kernel_launch(void* const* d_in, const int* in_sizes, int n_in,
                              void* d_out, int out_size, void* d_ws, size_t ws_size,
                              hipStream_t stream) {
  const float* q_in = (const float*)d_in[0];
  const float* k_in = (const float*)d_in[1];
  const float* v_in = (const float*)d_in[2];
  // d_in[3] = causal mask, unused (causality structural)
  const float* wq = (const float*)d_in[4];
  const float* wk = (const float*)d_in[5];
  const float* wv = (const float*)d_in[6];
  const float* wo = (const float*)d_in[7];

  char* ws = (char*)d_ws;
  const size_t MB = 1024ull * 1024ull;
  u16* Qp  = (u16*)(ws + 0  * MB);
  u16* Kp  = (u16*)(ws + 8  * MB);
  u16* Vt  = (u16*)(ws + 16 * MB);
  u16* Ctx = (u16*)(ws + 24 * MB);
  u16* Xq  = (u16*)(ws + 32 * MB);
  u16* Xk  = (u16*)(ws + 40 * MB);
  u16* Xv  = (u16*)(ws + 48 * MB);
  u16* Wqb = (u16*)(ws + 56 * MB);
  u16* Wkb = (u16*)(ws + 58 * MB);
  u16* Wvb = (u16*)(ws + 60 * MB);
  u16* Wob = (u16*)(ws + 62 * MB);

  cvt_kernel<<<dim3(4096, 7, 1), 256, 0, stream>>>(
      q_in, k_in, v_in, wq, wk, wv, wo, Xq, Xk, Xv, Wqb, Wkb, Wvb, Wob);
  qkv_proj_kernel<<<dim3(DM / BN, MTOT / BM, 3), 256, 0, stream>>>(
      Xq, Xk, Xv, Wqb, Wkb, Wvb, Qp, Kp, Vt);
  attn_kernel<<<dim3(2048), 256, 0, stream>>>(Qp, Kp, Vt, Ctx);
  out_proj_kernel<<<dim3(DM / BN, MTOT / BM), 256, 0, stream>>>(Ctx, Wob, (float*)d_out);
}

// Round 8
// 158.348 us; speedup vs baseline: 1.0226x; 1.0226x over previous
//
#include <hip/hip_runtime.h>
#include <hip/hip_bf16.h>
#include <cstdint>

// MultiHeadAttention: out = ( softmax(causal((X Wq^T)(X Wk^T)^T / 8)) (X Wv^T) ) Wo^T
// B=2, S=2048, D_MODEL=1024, H=16, D_HEAD=64. All MFMA bf16, accum fp32.
//
// Workspace layout (64 MB):
//  [0,8M)    Qp  bf16 [16][4096][64]  per-head packed, pre-scaled by log2e/8
//  [8,16M)   Kp  bf16 [16][4096][64]  per-head packed
//  [16,24M)  Vt  bf16 [1024][4096]    V transposed (row = h*64+d, col = token)
//  [24,32M)  Ctx bf16 [4096][1024]
//  [32,56M)  Xq/Xk/Xv bf16 inputs
//  [56,64M)  Wq/Wk/Wv/Wo bf16 weights

typedef unsigned short u16;
typedef u16 u16x4 __attribute__((ext_vector_type(4)));
typedef u16 u16x8 __attribute__((ext_vector_type(8)));
typedef unsigned u32x4 __attribute__((ext_vector_type(4)));
typedef __bf16 bf16x8 __attribute__((ext_vector_type(8)));
typedef float f32x4 __attribute__((ext_vector_type(4)));
typedef float f32x16 __attribute__((ext_vector_type(16)));

#define S_LEN 2048
#define DM 1024
#define NH 16
#define DH 64
#define BATCH 2
#define MTOT (BATCH*S_LEN)   // 4096

__device__ __forceinline__ u16 f2bf(float f) {
  union { float f; unsigned u; } v; v.f = f;
  unsigned r = v.u + 0x7FFFu + ((v.u >> 16) & 1u);   // RNE
  return (u16)(r >> 16);
}

__device__ __forceinline__ f32x4 mfma16(u16x8 a, u16x8 b, f32x4 c) {
  return __builtin_amdgcn_mfma_f32_16x16x32_bf16(
      __builtin_bit_cast(bf16x8, a), __builtin_bit_cast(bf16x8, b), c, 0, 0, 0);
}
__device__ __forceinline__ f32x16 mfma32(u16x8 a, u16x8 b, f32x16 c) {
  return __builtin_amdgcn_mfma_f32_32x32x16_bf16(
      __builtin_bit_cast(bf16x8, a), __builtin_bit_cast(bf16x8, b), c, 0, 0, 0);
}
__device__ __forceinline__ unsigned cvtpk_bf16(float lo, float hi) {
  unsigned r;
  asm("v_cvt_pk_bf16_f32 %0, %1, %2" : "=v"(r) : "v"(lo), "v"(hi));
  return r;
}
__device__ __forceinline__ void permswap(unsigned &a, unsigned &b) {
  asm volatile("v_permlane32_swap_b32 %0, %1" : "+v"(a), "+v"(b));
}
// async global -> LDS, 16B per lane; LDS dest = wave-uniform base + lane*16
__device__ __forceinline__ void gload16(const u16* g, u16* l) {
  __builtin_amdgcn_global_load_lds(
      (const __attribute__((address_space(1))) unsigned int*)g,
      (__attribute__((address_space(3))) unsigned int*)l, 16, 0, 0);
}

// ---------------------------------------------------------------- fp32->bf16
__global__ __launch_bounds__(256) void cvt_kernel(
    const float* __restrict__ s0, const float* __restrict__ s1,
    const float* __restrict__ s2, const float* __restrict__ s3,
    const float* __restrict__ s4, const float* __restrict__ s5,
    const float* __restrict__ s6,
    u16* __restrict__ d0, u16* __restrict__ d1, u16* __restrict__ d2,
    u16* __restrict__ d3, u16* __restrict__ d4, u16* __restrict__ d5,
    u16* __restrict__ d6) {
  const int y = blockIdx.y;
  const float* s; u16* d; int n;
  switch (y) {
    case 0: s = s0; d = d0; n = MTOT*DM; break;
    case 1: s = s1; d = d1; n = MTOT*DM; break;
    case 2: s = s2; d = d2; n = MTOT*DM; break;
    case 3: s = s3; d = d3; n = DM*DM;   break;
    case 4: s = s4; d = d4; n = DM*DM;   break;
    case 5: s = s5; d = d5; n = DM*DM;   break;
    default: s = s6; d = d6; n = DM*DM;  break;
  }
  int i = (blockIdx.x * 256 + threadIdx.x) * 4;
  if (i >= n) return;
  f32x4 v = *(const f32x4*)&s[i];
  u16x4 o;
  o[0] = f2bf(v[0]); o[1] = f2bf(v[1]); o[2] = f2bf(v[2]); o[3] = f2bf(v[3]);
  *(u16x4*)&d[i] = o;
}

// ---------------------------------------------------------------- GEMM C=A*B^T
// m97 structure: 128x128 tile, BK=32, 4 waves (2x2), global_load_lds width-16
// staging into LINEAR LDS [128][32], 2 barriers per K-step, 4x4 16x16x32 MFMA.
// MODE 0: bf16 out, per-head packed [16][4096][64], scaled.
// MODE 1: bf16 out, transposed [1024][4096] via LDS-transpose epilogue
//         (old direct scatter: 16 lanes x 8B at 8KB stride = 8x write
//          amplification; now full 128B-line coalesced).
// MODE 2: f32 out, plain [M][1024].
#define BM 128
#define BN 128
#define BKK 32

template<int MODE>
__device__ __forceinline__ void gemm_core(const u16* __restrict__ A,
                                          const u16* __restrict__ Bw,
                                          void* __restrict__ Cv,
                                          int K, float scale) {
  __shared__ u16 As[BM * BKK];
  __shared__ u16 Bs[BN * BKK];
  const int tid  = threadIdx.x;
  const int lane = tid & 63, w = tid >> 6;
  const int g = lane >> 4, r16 = lane & 15;
  const int wm = w >> 1, wn = w & 1;
  const int rowBase = blockIdx.y * BM;
  const int colBase = blockIdx.x * BN;
  f32x4 acc[4][4] = {};
  const int srow = lane >> 2;
  const int skc  = (lane & 3) * 8;
  const u16* gA[2]; const u16* gB[2]; u16* lA[2]; u16* lB[2];
#pragma unroll
  for (int j = 0; j < 2; j++) {
    const int c = w * 2 + j;
    gA[j] = &A [(size_t)(rowBase + c * 16 + srow) * K + skc];
    gB[j] = &Bw[(size_t)(colBase + c * 16 + srow) * K + skc];
    lA[j] = &As[c * 512];
    lB[j] = &Bs[c * 512];
  }
  for (int k0 = 0; k0 < K; k0 += BKK) {
    __syncthreads();
#pragma unroll
    for (int j = 0; j < 2; j++) {
      gload16(gA[j] + k0, lA[j]);
      gload16(gB[j] + k0, lB[j]);
    }
    __syncthreads();
    u16x8 af[4], bfv[4];
#pragma unroll
    for (int i = 0; i < 4; i++) af[i]  = *(const u16x8*)&As[(wm*64 + i*16 + r16) * BKK + g*8];
#pragma unroll
    for (int j = 0; j < 4; j++) bfv[j] = *(const u16x8*)&Bs[(wn*64 + j*16 + r16) * BKK + g*8];
    __builtin_amdgcn_s_setprio(1);
#pragma unroll
    for (int i = 0; i < 4; i++)
#pragma unroll
      for (int j = 0; j < 4; j++) acc[i][j] = mfma16(af[i], bfv[j], acc[i][j]);
    __builtin_amdgcn_s_setprio(0);
  }
  // C/D layout: col = lane&15, row = 4*(lane>>4)+reg
  if constexpr (MODE == 1) {
    // per-wave 64x64 transpose through LDS, coalesced Vt write
    __shared__ u16 TT[4][64 * 72];   // pad 72: 144B row stride (16B-mult)
    u16* T = TT[w];
#pragma unroll
    for (int i = 0; i < 4; i++)
#pragma unroll
      for (int j = 0; j < 4; j++)
#pragma unroll
        for (int r = 0; r < 4; r++)
          T[(j * 16 + r16) * 72 + i * 16 + 4 * g + r] = f2bf(acc[i][j][r]);
    __syncthreads();
    const int dl0 = lane >> 3, tc = lane & 7;
    u16* O = (u16*)Cv;
#pragma unroll
    for (int p = 0; p < 8; p++) {
      int dl = p * 8 + dl0;
      u16x8 vv = *(const u16x8*)&T[dl * 72 + tc * 8];
      *(u16x8*)&O[(size_t)(colBase + wn * 64 + dl) * MTOT + rowBase + wm * 64 + tc * 8] = vv;
    }
  } else {
#pragma unroll
    for (int i = 0; i < 4; i++) {
#pragma unroll
      for (int j = 0; j < 4; j++) {
        int row = rowBase + wm*64 + i*16 + 4*g;
        int col = colBase + wn*64 + j*16 + r16;
        if (MODE == 0) {
          u16* O = (u16*)Cv;
          int head = col >> 6, d = col & 63;
#pragma unroll
          for (int r = 0; r < 4; r++)
            O[((size_t)head * MTOT + row + r) * DH + d] = f2bf(acc[i][j][r] * scale);
        } else {
#pragma unroll
          for (int r = 0; r < 4; r++)
            ((float*)Cv)[(size_t)(row + r) * DM + col] = acc[i][j][r];
        }
      }
    }
  }
}

__global__ __launch_bounds__(256) void qk_proj_kernel(
    const u16* __restrict__ Xq, const u16* __restrict__ Xk,
    const u16* __restrict__ Wq, const u16* __restrict__ Wk,
    u16* __restrict__ Qp, u16* __restrict__ Kp) {
  // Q pre-scaled by (1/sqrt(64)) * log2(e) -> softmax in exp2 domain
  if (blockIdx.z == 0) gemm_core<0>(Xq, Wq, Qp, DM, 0.125f * 1.44269504f);
  else                 gemm_core<0>(Xk, Wk, Kp, DM, 1.0f);
}

__global__ __launch_bounds__(256) void v_proj_kernel(
    const u16* __restrict__ Xv, const u16* __restrict__ Wv, u16* __restrict__ Vt) {
  gemm_core<1>(Xv, Wv, Vt, DM, 1.0f);
}

__global__ __launch_bounds__(256) void out_proj_kernel(
    const u16* __restrict__ Ctx, const u16* __restrict__ Wo, float* __restrict__ Out) {
  gemm_core<2>(Ctx, Wo, Out, DM, 1.0f);
}

// ---------------------------------------------------------------- flash attn
// Round-8 restructure: K/V tiles staged into LDS (coalesced gload16 bursts)
// shared by the block's 2 waves, instead of per-lane register gathers whose
// every load spanned 32 cache lines (TA-throughput bound; rounds 5-7 all
// plateaued ~75us at MfmaUtil 9%). XOR-swizzled LDS (T2) via pre-swizzled
// global source (m173: gload_lds dest must be linear). Double-buffered,
// ONE barrier per tile (stage t+1 -> compute t -> barrier). No kv-split,
// no merge: both waves have identical tile counts (ntb = qc+1).
// Grid 1024 blocks x 128 threads (2 waves x 32 q-rows = 64-q block).
// Kept: swapped QK^T, exp2 softmax, T12 cvt_pk+permlane, T13 defer-max,
// T5 setprio, XCD-bijective remap (heads interleaved, heavy-first).
#define KVB 64

#define STAGE(B, T)                                                            \
  {                                                                            \
    const int kv0_ = (T) * KVB;                                                \
    _Pragma("unroll")                                                          \
    for (int j = 0; j < 4; j++) {                                              \
      const int rb = wv * 32 + j * 8;                                          \
      gload16(&Kbase[(size_t)(kv0_ + rb + srow) * DH + sc16 * 8],              \
              &Kl[B][rb * 64]);                                                \
      gload16(&Vbase[(size_t)(rb + srow) * MTOT + kv0_ + sc16 * 8],            \
              &Vl[B][rb * 64]);                                                \
    }                                                                          \
  }

#define TILE_BODY(BUF, T)                                                      \
  {                                                                            \
    const int kv0 = (T) * KVB;                                                 \
    u16x8 kf[8];                                                               \
    _Pragma("unroll")                                                          \
    for (int ds = 0; ds < 4; ds++) {                                           \
      kf[2*ds]   = *(const u16x8*)&Kl[BUF][(q32)      * 64 + (((ds*2+hi) ^ (q32 & 7)) * 8)]; \
      kf[2*ds+1] = *(const u16x8*)&Kl[BUF][(32 + q32) * 64 + (((ds*2+hi) ^ (q32 & 7)) * 8)]; \
    }                                                                          \
    f32x16 s0 = {}, s1 = {};                                                   \
    __builtin_amdgcn_s_setprio(1);                                             \
    _Pragma("unroll")                                                          \
    for (int ds = 0; ds < 4; ds++) {                                           \
      s0 = mfma32(kf[2*ds],   qf[ds], s0);                                     \
      s1 = mfma32(kf[2*ds+1], qf[ds], s1);                                     \
    }                                                                          \
    __builtin_amdgcn_s_setprio(0);                                             \
    u16x8 vf[8];                                                               \
    _Pragma("unroll")                                                          \
    for (int ks = 0; ks < 4; ks++) {                                           \
      vf[2*ks]   = *(const u16x8*)&Vl[BUF][(q32)      * 64 + (((ks*2+hi) ^ (q32 & 7)) * 8)]; \
      vf[2*ks+1] = *(const u16x8*)&Vl[BUF][(32 + q32) * 64 + (((ks*2+hi) ^ (q32 & 7)) * 8)]; \
    }                                                                          \
    if ((T) == ntb - 1) {                                                      \
      const int qg = qbase + q32;                                              \
      _Pragma("unroll")                                                        \
      for (int r = 0; r < 16; r++) {                                           \
        int kvr = kv0 + (r & 3) + 8 * (r >> 2) + 4 * hi;                       \
        if (kvr > qg)      s0[r] = -1e30f;                                     \
        if (kvr + 32 > qg) s1[r] = -1e30f;                                     \
      }                                                                        \
    }                                                                          \
    float mx[8];                                                               \
    _Pragma("unroll")                                                          \
    for (int r = 0; r < 8; r++)                                                \
      mx[r] = fmaxf(fmaxf(s0[r], s0[r + 8]), fmaxf(s1[r], s1[r + 8]));         \
    _Pragma("unroll")                                                          \
    for (int r = 0; r < 4; r++) mx[r] = fmaxf(mx[r], mx[r + 4]);               \
    float pmax = fmaxf(fmaxf(mx[0], mx[2]), fmaxf(mx[1], mx[3]));              \
    pmax = fmaxf(pmax, __shfl_xor(pmax, 32, 64));                              \
    if (__ballot(pmax > m + 11.5f)) {   /* defer-max, THR = 8/ln2 */           \
      float mnew = fmaxf(m, pmax);                                             \
      float alpha = exp2f(m - mnew);                                           \
      l *= alpha; m = mnew;                                                    \
      _Pragma("unroll")                                                        \
      for (int r = 0; r < 16; r++) {                                           \
        float fsc = __shfl(alpha, (r & 3) + 8 * (r >> 2) + 4 * hi, 64);        \
        ctx0[r] *= fsc; ctx1[r] *= fsc;                                        \
      }                                                                        \
    }                                                                          \
    _Pragma("unroll")                                                          \
    for (int r = 0; r < 16; r++) s0[r] = exp2f(s0[r] - m);                     \
    _Pragma("unroll")                                                          \
    for (int r = 0; r < 16; r++) s1[r] = exp2f(s1[r] - m);                     \
    f32x16 sv = s0 + s1;                                                       \
    float p8[8];                                                               \
    _Pragma("unroll")                                                          \
    for (int r = 0; r < 8; r++) p8[r] = sv[r] + sv[r + 8];                     \
    _Pragma("unroll")                                                          \
    for (int r = 0; r < 4; r++) p8[r] += p8[r + 4];                            \
    float psum = (p8[0] + p8[2]) + (p8[1] + p8[3]);                            \
    psum += __shfl_xor(psum, 32, 64);                                          \
    l += psum;                                                                 \
    u16x8 pa[4];                                                               \
    _Pragma("unroll")                                                          \
    for (int tt = 0; tt < 2; tt++) {                                           \
      unsigned pk[8];                                                          \
      _Pragma("unroll")                                                        \
      for (int i = 0; i < 8; i++)                                              \
        pk[i] = cvtpk_bf16(tt ? s1[2*i] : s0[2*i], tt ? s1[2*i+1] : s0[2*i+1]);\
      permswap(pk[0], pk[2]); permswap(pk[1], pk[3]);                          \
      permswap(pk[4], pk[6]); permswap(pk[5], pk[7]);                          \
      u32x4 w0 = {pk[0], pk[1], pk[2], pk[3]};                                 \
      u32x4 w1 = {pk[4], pk[5], pk[6], pk[7]};                                 \
      pa[2*tt]   = __builtin_bit_cast(u16x8, w0);                              \
      pa[2*tt+1] = __builtin_bit_cast(u16x8, w1);                              \
    }                                                                          \
    __builtin_amdgcn_s_setprio(1);                                             \
    _Pragma("unroll")                                                          \
    for (int ks = 0; ks < 4; ks++) {                                           \
      ctx0 = mfma32(pa[ks], vf[2*ks],   ctx0);                                 \
      ctx1 = mfma32(pa[ks], vf[2*ks+1], ctx1);                                 \
    }                                                                          \
    __builtin_amdgcn_s_setprio(0);                                             \
  }

__global__ __launch_bounds__(128, 4) void attn_kernel(const u16* __restrict__ Qp,
                                                      const u16* __restrict__ Kp,
                                                      const u16* __restrict__ Vt,
                                                      u16* __restrict__ Ctx) {
  __shared__ u16 Kl[2][KVB * 64];   // [buf][kv row][d], 16B-chunk XOR-swizzled
  __shared__ u16 Vl[2][KVB * 64];   // [buf][d row][token], same swizzle
  const int tid = threadIdx.x;
  const int lane = tid & 63, wv = tid >> 6;      // 2 waves
  const int q32 = lane & 31, hi = lane >> 5;
  // XCD remap (assumes XCD = flat % 8): XCD owns 4 heads, blocks interleave
  // heads (round-6 order), heavy q-chunks first.
  const int flat = blockIdx.x;                 // 0..1023
  const int xcd = flat & 7, idx = flat >> 3;   // idx 0..127
  const int bh = xcd * 4 + (idx & 3);
  const int qc = 31 - (idx >> 2);              // 0..31, heavy first
  const int bb = bh >> 4, h = bh & 15;
  const int qbase = qc * 64 + wv * 32;

  const u16* Qbase = Qp + (size_t)(h * MTOT + bb * S_LEN) * DH;
  const u16* Kbase = Kp + (size_t)(h * MTOT + bb * S_LEN) * DH;
  const u16* Vbase = Vt + (size_t)(h * DH) * MTOT + bb * S_LEN;

  u16x8 qf[4];
#pragma unroll
  for (int ds = 0; ds < 4; ds++)
    qf[ds] = *(const u16x8*)&Qbase[(size_t)(qbase + q32) * DH + ds * 16 + hi * 8];

  f32x16 ctx0 = {}, ctx1 = {};
  float m = -3.0e38f, l = 0.f;
  const int ntb = qc + 1;            // identical for both waves (no idle wave)

  // staging lane geometry: lane covers (row srow, 16B chunk), source chunk
  // pre-swizzled so LDS(r,c) = G(r, c^(r&7)) with a LINEAR gload_lds dest.
  const int srow = lane >> 3;                  // 0..7
  const int sc16 = (lane & 7) ^ srow;          // swizzled source chunk

  STAGE(0, 0);
  int cur = 0;
  for (int t = 0; t < ntb; ++t) {
    __syncthreads();                 // stage(t) landed; prev reads done
    if (t + 1 < ntb) STAGE(cur ^ 1, t + 1);
    TILE_BODY(cur, t);
    cur ^= 1;
  }

  float linv = 1.f / l;
#pragma unroll
  for (int r = 0; r < 16; r++) {
    int qr = (r & 3) + 8 * (r >> 2) + 4 * hi;
    float fl = __shfl(linv, qr, 64);
    size_t grow = (size_t)(bb * S_LEN + qbase + qr) * DM + h * DH;
    Ctx[grow + q32]      = f2bf(ctx0[r] * fl);
    Ctx[grow + 32 + q32] = f2bf(ctx1[r] * fl);
  }
}

// ---------------------------------------------------------------- launch
extern "C" void kernel_launch(void* const* d_in, const int* in_sizes, int n_in,
                              void* d_out, int out_size, void* d_ws, size_t ws_size,
                              hipStream_t stream) {
  const float* q_in = (const float*)d_in[0];
  const float* k_in = (const float*)d_in[1];
  const float* v_in = (const float*)d_in[2];
  // d_in[3] = causal mask, unused (causality structural)
  const float* wq = (const float*)d_in[4];
  const float* wk = (const float*)d_in[5];
  const float* wv = (const float*)d_in[6];
  const float* wo = (const float*)d_in[7];

  char* ws = (char*)d_ws;
  const size_t MB = 1024ull * 1024ull;
  u16* Qp  = (u16*)(ws + 0  * MB);
  u16* Kp  = (u16*)(ws + 8  * MB);
  u16* Vt  = (u16*)(ws + 16 * MB);
  u16* Ctx = (u16*)(ws + 24 * MB);
  u16* Xq  = (u16*)(ws + 32 * MB);
  u16* Xk  = (u16*)(ws + 40 * MB);
  u16* Xv  = (u16*)(ws + 48 * MB);
  u16* Wqb = (u16*)(ws + 56 * MB);
  u16* Wkb = (u16*)(ws + 58 * MB);
  u16* Wvb = (u16*)(ws + 60 * MB);
  u16* Wob = (u16*)(ws + 62 * MB);

  cvt_kernel<<<dim3(4096, 7, 1), 256, 0, stream>>>(
      q_in, k_in, v_in, wq, wk, wv, wo, Xq, Xk, Xv, Wqb, Wkb, Wvb, Wob);
  qk_proj_kernel<<<dim3(DM / BN, MTOT / BM, 2), 256, 0, stream>>>(
      Xq, Xk, Wqb, Wkb, Qp, Kp);
  v_proj_kernel<<<dim3(DM / BN, MTOT / BM), 256, 0, stream>>>(Xv, Wvb, Vt);
  attn_kernel<<<dim3(1024), 128, 0, stream>>>(Qp, Kp, Vt, Ctx);
  out_proj_kernel<<<dim3(DM / BN, MTOT / BM), 256, 0, stream>>>(Ctx, Wob, (float*)d_out);
}

// Round 9
// 130.037 us; speedup vs baseline: 1.2453x; 1.2177x over previous
//
#include <hip/hip_runtime.h>
#include <hip/hip_bf16.h>
#include <cstdint>

// MultiHeadAttention: out = ( softmax(causal((X Wq^T)(X Wk^T)^T / 8)) (X Wv^T) ) Wo^T
// B=2, S=2048, D_MODEL=1024, H=16, D_HEAD=64. All MFMA bf16, accum fp32.
//
// Workspace layout (64 MB):
//  [0,8M)    Qp  bf16 [16][4096][64]  per-head packed, pre-scaled by log2e/8
//  [8,16M)   Kp  bf16 [16][4096][64]  per-head packed
//  [16,24M)  Vt  bf16 [1024][4096]    V transposed (row = h*64+d, col = token)
//  [24,32M)  Ctx bf16 [4096][1024]
//  [32,56M)  Xq/Xk/Xv bf16 inputs
//  [56,64M)  Wq/Wk/Wv/Wo bf16 weights

typedef unsigned short u16;
typedef u16 u16x4 __attribute__((ext_vector_type(4)));
typedef u16 u16x8 __attribute__((ext_vector_type(8)));
typedef unsigned u32x4 __attribute__((ext_vector_type(4)));
typedef __bf16 bf16x8 __attribute__((ext_vector_type(8)));
typedef float f32x4 __attribute__((ext_vector_type(4)));

#define S_LEN 2048
#define DM 1024
#define NH 16
#define DH 64
#define BATCH 2
#define MTOT (BATCH*S_LEN)   // 4096

__device__ __forceinline__ u16 f2bf(float f) {
  union { float f; unsigned u; } v; v.f = f;
  unsigned r = v.u + 0x7FFFu + ((v.u >> 16) & 1u);   // RNE
  return (u16)(r >> 16);
}

__device__ __forceinline__ f32x4 mfma16(u16x8 a, u16x8 b, f32x4 c) {
  return __builtin_amdgcn_mfma_f32_16x16x32_bf16(
      __builtin_bit_cast(bf16x8, a), __builtin_bit_cast(bf16x8, b), c, 0, 0, 0);
}
__device__ __forceinline__ unsigned cvtpk_bf16(float lo, float hi) {
  unsigned r;
  asm("v_cvt_pk_bf16_f32 %0, %1, %2" : "=v"(r) : "v"(lo), "v"(hi));
  return r;
}
// async global -> LDS, 16B per lane; LDS dest = wave-uniform base + lane*16
__device__ __forceinline__ void gload16(const u16* g, u16* l) {
  __builtin_amdgcn_global_load_lds(
      (const __attribute__((address_space(1))) unsigned int*)g,
      (__attribute__((address_space(3))) unsigned int*)l, 16, 0, 0);
}

// ---------------------------------------------------------------- fp32->bf16
__global__ __launch_bounds__(256) void cvt_kernel(
    const float* __restrict__ s0, const float* __restrict__ s1,
    const float* __restrict__ s2, const float* __restrict__ s3,
    const float* __restrict__ s4, const float* __restrict__ s5,
    const float* __restrict__ s6,
    u16* __restrict__ d0, u16* __restrict__ d1, u16* __restrict__ d2,
    u16* __restrict__ d3, u16* __restrict__ d4, u16* __restrict__ d5,
    u16* __restrict__ d6) {
  const int y = blockIdx.y;
  const float* s; u16* d; int n;
  switch (y) {
    case 0: s = s0; d = d0; n = MTOT*DM; break;
    case 1: s = s1; d = d1; n = MTOT*DM; break;
    case 2: s = s2; d = d2; n = MTOT*DM; break;
    case 3: s = s3; d = d3; n = DM*DM;   break;
    case 4: s = s4; d = d4; n = DM*DM;   break;
    case 5: s = s5; d = d5; n = DM*DM;   break;
    default: s = s6; d = d6; n = DM*DM;  break;
  }
  int i = (blockIdx.x * 256 + threadIdx.x) * 4;
  if (i >= n) return;
  f32x4 v = *(const f32x4*)&s[i];
  u16x4 o;
  o[0] = f2bf(v[0]); o[1] = f2bf(v[1]); o[2] = f2bf(v[2]); o[3] = f2bf(v[3]);
  *(u16x4*)&d[i] = o;
}

// ---------------------------------------------------------------- GEMM C=A*B^T
// m97 structure (round-6 config): 128x128 tile, BK=32, 4 waves (2x2),
// global_load_lds width-16 into LINEAR LDS, 2 barriers/K-step, 4x4 MFMA.
#define BM 128
#define BN 128
#define BKK 32

template<int MODE>
__device__ __forceinline__ void gemm_core(const u16* __restrict__ A,
                                          const u16* __restrict__ Bw,
                                          void* __restrict__ Cv,
                                          int K, float scale) {
  __shared__ u16 As[BM * BKK];
  __shared__ u16 Bs[BN * BKK];
  const int tid  = threadIdx.x;
  const int lane = tid & 63, w = tid >> 6;
  const int g = lane >> 4, r16 = lane & 15;
  const int wm = w >> 1, wn = w & 1;
  const int rowBase = blockIdx.y * BM;
  const int colBase = blockIdx.x * BN;
  f32x4 acc[4][4] = {};
  const int srow = lane >> 2;
  const int skc  = (lane & 3) * 8;
  const u16* gA[2]; const u16* gB[2]; u16* lA[2]; u16* lB[2];
#pragma unroll
  for (int j = 0; j < 2; j++) {
    const int c = w * 2 + j;
    gA[j] = &A [(size_t)(rowBase + c * 16 + srow) * K + skc];
    gB[j] = &Bw[(size_t)(colBase + c * 16 + srow) * K + skc];
    lA[j] = &As[c * 512];
    lB[j] = &Bs[c * 512];
  }
  for (int k0 = 0; k0 < K; k0 += BKK) {
    __syncthreads();
#pragma unroll
    for (int j = 0; j < 2; j++) {
      gload16(gA[j] + k0, lA[j]);
      gload16(gB[j] + k0, lB[j]);
    }
    __syncthreads();
    u16x8 af[4], bfv[4];
#pragma unroll
    for (int i = 0; i < 4; i++) af[i]  = *(const u16x8*)&As[(wm*64 + i*16 + r16) * BKK + g*8];
#pragma unroll
    for (int j = 0; j < 4; j++) bfv[j] = *(const u16x8*)&Bs[(wn*64 + j*16 + r16) * BKK + g*8];
    __builtin_amdgcn_s_setprio(1);
#pragma unroll
    for (int i = 0; i < 4; i++)
#pragma unroll
      for (int j = 0; j < 4; j++) acc[i][j] = mfma16(af[i], bfv[j], acc[i][j]);
    __builtin_amdgcn_s_setprio(0);
  }
  // C/D layout: col = lane&15, row = 4*(lane>>4)+reg
#pragma unroll
  for (int i = 0; i < 4; i++) {
#pragma unroll
    for (int j = 0; j < 4; j++) {
      int row = rowBase + wm*64 + i*16 + 4*g;
      int col = colBase + wn*64 + j*16 + r16;
      if (MODE == 0) {
        u16* O = (u16*)Cv;
        int head = col >> 6, d = col & 63;
#pragma unroll
        for (int r = 0; r < 4; r++)
          O[((size_t)head * MTOT + row + r) * DH + d] = f2bf(acc[i][j][r] * scale);
      } else if (MODE == 1) {
        u16x4 o;
#pragma unroll
        for (int r = 0; r < 4; r++) o[r] = f2bf(acc[i][j][r]);
        *(u16x4*)&((u16*)Cv)[(size_t)col * MTOT + row] = o;
      } else {
#pragma unroll
        for (int r = 0; r < 4; r++)
          ((float*)Cv)[(size_t)(row + r) * DM + col] = acc[i][j][r];
      }
    }
  }
}

__global__ __launch_bounds__(256) void qkv_proj_kernel(
    const u16* __restrict__ Xq, const u16* __restrict__ Xk, const u16* __restrict__ Xv,
    const u16* __restrict__ Wq, const u16* __restrict__ Wk, const u16* __restrict__ Wv,
    u16* __restrict__ Qp, u16* __restrict__ Kp, u16* __restrict__ Vt) {
  const int z = blockIdx.z;
  // Q pre-scaled by (1/sqrt(64)) * log2(e) -> softmax in exp2 domain
  if (z == 0)      gemm_core<0>(Xq, Wq, Qp, DM, 0.125f * 1.44269504f);
  else if (z == 1) gemm_core<0>(Xk, Wk, Kp, DM, 1.0f);
  else             gemm_core<1>(Xv, Wv, Vt, DM, 1.0f);
}

__global__ __launch_bounds__(256) void out_proj_kernel(
    const u16* __restrict__ Ctx, const u16* __restrict__ Wo, float* __restrict__ Out) {
  gemm_core<2>(Ctx, Wo, Out, DM, 1.0f);
}

// ---------------------------------------------------------------- flash attn
// Round-9: 16 q-rows/WAVE (16x16x32 MFMA) -> 4096 waves (2x round 8's 2048).
// Block = 64 q, 4 waves share dbuf-staged K/V LDS (32KB); per-wave 2KB
// swizzled P buffer for the in-LDS P->A-frag transpose. Total LDS = 40KB
// exactly -> 4 blocks/CU x 4 waves = 4 waves/SIMD resident (round 8: ~1,
// everything latency-exposed at 12.5% occupancy). ntb = qc+1 uniform for
// all 4 waves (64-q-aligned blocks) -> no idle waves, uniform barriers.
// Kept: swapped QK^T (lane owns q-col), exp2 softmax, T13 defer-max, T5
// setprio, XOR-swizzled LDS via pre-swizzled gload source, XCD remap.

#define STAGE(B, T)                                                            \
  {                                                                            \
    const int kv0_ = (T) * 64;                                                 \
    _Pragma("unroll")                                                          \
    for (int j = 0; j < 2; j++) {                                              \
      const int rb = wv * 16 + j * 8;                                          \
      gload16(&Kbase[(size_t)(kv0_ + rb + srow) * DH + sc16 * 8],              \
              &Kl[B][rb * 64]);                                                \
      gload16(&Vbase[(size_t)(rb + srow) * MTOT + kv0_ + sc16 * 8],            \
              &Vl[B][rb * 64]);                                                \
    }                                                                          \
  }

#define TILE_BODY(BUF, T)                                                      \
  {                                                                            \
    const int kv0 = (T) * 64;                                                  \
    f32x4 s[4] = {};                                                           \
    __builtin_amdgcn_s_setprio(1);                                             \
    _Pragma("unroll")                                                          \
    for (int f = 0; f < 4; f++) {                                              \
      _Pragma("unroll")                                                        \
      for (int ds = 0; ds < 2; ds++) {                                         \
        u16x8 kf = *(const u16x8*)&Kl[BUF][(f * 16 + q16) * 64 +               \
                                           ((ds * 4 + g) ^ qx7) * 8];          \
        s[f] = mfma16(kf, qf[ds], s[f]);                                       \
      }                                                                        \
    }                                                                          \
    __builtin_amdgcn_s_setprio(0);                                             \
    if ((T) == ntb - 1) {      /* only last tile crosses the diagonal */       \
      const int qg = qb16 + q16;                                               \
      _Pragma("unroll")                                                        \
      for (int f = 0; f < 4; f++)                                              \
        _Pragma("unroll")                                                      \
        for (int r = 0; r < 4; r++)                                            \
          if (kv0 + f * 16 + 4 * g + r > qg) s[f][r] = -1e30f;                 \
    }                                                                          \
    float mx[4];                                                               \
    _Pragma("unroll")                                                          \
    for (int r = 0; r < 4; r++)                                                \
      mx[r] = fmaxf(fmaxf(s[0][r], s[1][r]), fmaxf(s[2][r], s[3][r]));         \
    float pmax = fmaxf(fmaxf(mx[0], mx[1]), fmaxf(mx[2], mx[3]));              \
    pmax = fmaxf(pmax, __shfl_xor(pmax, 16, 64));                              \
    pmax = fmaxf(pmax, __shfl_xor(pmax, 32, 64));                              \
    if (__ballot(pmax > m + 11.5f)) {   /* defer-max, THR = 8/ln2 */           \
      float mnew = fmaxf(m, pmax);                                             \
      float alpha = exp2f(m - mnew);                                           \
      l *= alpha; m = mnew;                                                    \
      float fsc[4];                                                            \
      _Pragma("unroll")                                                        \
      for (int r = 0; r < 4; r++) fsc[r] = __shfl(alpha, 4 * g + r, 64);       \
      _Pragma("unroll")                                                        \
      for (int dt = 0; dt < 4; dt++)                                           \
        _Pragma("unroll")                                                      \
        for (int r = 0; r < 4; r++) ctx[dt][r] *= fsc[r];                      \
    }                                                                          \
    _Pragma("unroll")                                                          \
    for (int f = 0; f < 4; f++)                                                \
      _Pragma("unroll")                                                        \
      for (int r = 0; r < 4; r++) s[f][r] = exp2f(s[f][r] - m);                \
    f32x4 sv = (s[0] + s[1]) + (s[2] + s[3]);                                  \
    float psum = (sv[0] + sv[1]) + (sv[2] + sv[3]);                            \
    psum += __shfl_xor(psum, 16, 64);                                          \
    psum += __shfl_xor(psum, 32, 64);                                          \
    l += psum;                                                                 \
    /* P (16q x 64kv) -> per-wave swizzled LDS, then read as A-frags */        \
    _Pragma("unroll")                                                          \
    for (int f = 0; f < 4; f++) {                                              \
      const int cidx = (((2 * f + (g >> 1)) ^ qx7) * 8) + 4 * (g & 1);         \
      *(unsigned*)&P16[q16 * 64 + cidx]     = cvtpk_bf16(s[f][0], s[f][1]);    \
      *(unsigned*)&P16[q16 * 64 + cidx + 2] = cvtpk_bf16(s[f][2], s[f][3]);    \
    }                                                                          \
    asm volatile("s_waitcnt lgkmcnt(0)" ::: "memory");                         \
    __builtin_amdgcn_sched_barrier(0);                                         \
    u16x8 pa0 = *(const u16x8*)&P16[q16 * 64 + ((g)     ^ qx7) * 8];           \
    u16x8 pa1 = *(const u16x8*)&P16[q16 * 64 + ((4 + g) ^ qx7) * 8];           \
    __builtin_amdgcn_s_setprio(1);                                             \
    _Pragma("unroll")                                                          \
    for (int dt = 0; dt < 4; dt++) {                                           \
      u16x8 vf0 = *(const u16x8*)&Vl[BUF][(dt * 16 + q16) * 64 +               \
                                          ((g)     ^ qx7) * 8];                \
      u16x8 vf1 = *(const u16x8*)&Vl[BUF][(dt * 16 + q16) * 64 +               \
                                          ((4 + g) ^ qx7) * 8];                \
      ctx[dt] = mfma16(pa0, vf0, ctx[dt]);                                     \
      ctx[dt] = mfma16(pa1, vf1, ctx[dt]);                                     \
    }                                                                          \
    __builtin_amdgcn_s_setprio(0);                                             \
  }

__global__ __launch_bounds__(256, 4) void attn_kernel(const u16* __restrict__ Qp,
                                                      const u16* __restrict__ Kp,
                                                      const u16* __restrict__ Vt,
                                                      u16* __restrict__ Ctx) {
  __shared__ u16 Kl[2][64 * 64];    // dbuf K tile [kv][d], chunk-XOR-swizzled
  __shared__ u16 Vl[2][64 * 64];    // dbuf V tile [d][token], same swizzle
  __shared__ u16 Pl[4][16 * 64];    // per-wave P, chunk-XOR-swizzled
  const int tid = threadIdx.x;
  const int lane = tid & 63, wv = tid >> 6;      // 4 waves
  const int q16 = lane & 15, g = lane >> 4;
  const int qx7 = q16 & 7;
  // XCD remap (assumes XCD = flat % 8): XCD owns 4 heads interleaved,
  // heavy q-chunks dispatch first.
  const int flat = blockIdx.x;                 // 0..1023
  const int xcd = flat & 7, idx = flat >> 3;   // idx 0..127
  const int bh = xcd * 4 + (idx & 3);
  const int qc = 31 - (idx >> 2);              // 0..31, heavy first
  const int bb = bh >> 4, h = bh & 15;
  const int qb16 = qc * 64 + wv * 16;          // this wave's 16-q base

  const u16* Qbase = Qp + (size_t)(h * MTOT + bb * S_LEN) * DH;
  const u16* Kbase = Kp + (size_t)(h * MTOT + bb * S_LEN) * DH;
  const u16* Vbase = Vt + (size_t)(h * DH) * MTOT + bb * S_LEN;
  u16* P16 = Pl[wv];

  // Q B-frags: b[j] = Q[q=lane&15][d = ds*32 + 8g + j]
  u16x8 qf[2];
#pragma unroll
  for (int ds = 0; ds < 2; ds++)
    qf[ds] = *(const u16x8*)&Qbase[(size_t)(qb16 + q16) * DH + ds * 32 + g * 8];

  f32x4 ctx[4] = {};
  float m = -3.0e38f, l = 0.f;
  const int ntb = qc + 1;            // identical for all 4 waves

  // staging lane geometry: 8 rows x 8 chunks per gload; source chunk
  // pre-swizzled so LDS(r,c) = G(r, c ^ (r&7)) with LINEAR gload dest.
  const int srow = lane >> 3;                  // 0..7
  const int sc16 = (lane & 7) ^ srow;          // swizzled source chunk

  STAGE(0, 0);
  int cur = 0;
  for (int t = 0; t < ntb; ++t) {
    __syncthreads();                 // stage(t) landed; prev reads done
    if (t + 1 < ntb) STAGE(cur ^ 1, t + 1);
    TILE_BODY(cur, t);
    cur ^= 1;
  }

  const float linv = 1.f / l;
  float flv[4];
#pragma unroll
  for (int r = 0; r < 4; r++) flv[r] = __shfl(linv, 4 * g + r, 64);
#pragma unroll
  for (int dt = 0; dt < 4; dt++)
#pragma unroll
    for (int r = 0; r < 4; r++) {
      size_t grow = (size_t)(bb * S_LEN + qb16 + 4 * g + r) * DM + h * DH;
      Ctx[grow + dt * 16 + q16] = f2bf(ctx[dt][r] * flv[r]);
    }
}

// ---------------------------------------------------------------- launch
extern "C" void kernel_launch(void* const* d_in, const int* in_sizes, int n_in,
                              void* d_out, int out_size, void* d_ws, size_t ws_size,
                              hipStream_t stream) {
  const float* q_in = (const float*)d_in[0];
  const float* k_in = (const float*)d_in[1];
  const float* v_in = (const float*)d_in[2];
  // d_in[3] = causal mask, unused (causality structural)
  const float* wq = (const float*)d_in[4];
  const float* wk = (const float*)d_in[5];
  const float* wv = (const float*)d_in[6];
  const float* wo = (const float*)d_in[7];

  char* ws = (char*)d_ws;
  const size_t MB = 1024ull * 1024ull;
  u16* Qp  = (u16*)(ws + 0  * MB);
  u16* Kp  = (u16*)(ws + 8  * MB);
  u16* Vt  = (u16*)(ws + 16 * MB);
  u16* Ctx = (u16*)(ws + 24 * MB);
  u16* Xq  = (u16*)(ws + 32 * MB);
  u16* Xk  = (u16*)(ws + 40 * MB);
  u16* Xv  = (u16*)(ws + 48 * MB);
  u16* Wqb = (u16*)(ws + 56 * MB);
  u16* Wkb = (u16*)(ws + 58 * MB);
  u16* Wvb = (u16*)(ws + 60 * MB);
  u16* Wob = (u16*)(ws + 62 * MB);

  cvt_kernel<<<dim3(4096, 7, 1), 256, 0, stream>>>(
      q_in, k_in, v_in, wq, wk, wv, wo, Xq, Xk, Xv, Wqb, Wkb, Wvb, Wob);
  qkv_proj_kernel<<<dim3(DM / BN, MTOT / BM, 3), 256, 0, stream>>>(
      Xq, Xk, Xv, Wqb, Wkb, Wvb, Qp, Kp, Vt);
  attn_kernel<<<dim3(1024), 256, 0, stream>>>(Qp, Kp, Vt, Ctx);
  out_proj_kernel<<<dim3(DM / BN, MTOT / BM), 256, 0, stream>>>(Ctx, Wob, (float*)d_out);
}